// Round 5
// baseline (599.641 us; speedup 1.0000x reference)
//
#include <hip/hip_runtime.h>
#include <stdint.h>

// PointerNetwork forward, MI355X/gfx950.
// x-chain and h-chain are sampling-independent; scores for unvisited slots
// don't depend on WHICH slots are visited => precompute all, sample cheaply.
// B=256, S=64, H=128.
// RNG: JAX threefry2x32 partitionable mode: bits = o0^o1 of tf(key,(0,j)).
// GEMM structure: K=128, tiny M => weights-in-VGPR matvec (k3 pattern minus
// the serial barriers), NOT LDS-tile GEMM (R4 post-mortem: tile GEMM was
// latency-bound at 98us vs 10us floor, w/ bank conflicts + suspected spills).

#define BN 256
#define SN 64
#define HN 128
#define NEGV (-1.0e9f)
#define TINYF 1.17549435e-38f

__device__ __forceinline__ uint32_t rotl32(uint32_t v, int d) {
  return (v << d) | (v >> (32 - d));
}

__device__ __forceinline__ void threefry2x32(uint32_t k0, uint32_t k1,
                                             uint32_t x0, uint32_t x1,
                                             uint32_t& o0, uint32_t& o1) {
  uint32_t ks2 = k0 ^ k1 ^ 0x1BD11BDAu;
  x0 += k0; x1 += k1;
  x0 += x1; x1 = rotl32(x1, 13); x1 ^= x0;
  x0 += x1; x1 = rotl32(x1, 15); x1 ^= x0;
  x0 += x1; x1 = rotl32(x1, 26); x1 ^= x0;
  x0 += x1; x1 = rotl32(x1, 6);  x1 ^= x0;
  x0 += k1; x1 += ks2 + 1u;
  x0 += x1; x1 = rotl32(x1, 17); x1 ^= x0;
  x0 += x1; x1 = rotl32(x1, 29); x1 ^= x0;
  x0 += x1; x1 = rotl32(x1, 16); x1 ^= x0;
  x0 += x1; x1 = rotl32(x1, 24); x1 ^= x0;
  x0 += ks2; x1 += k0 + 2u;
  x0 += x1; x1 = rotl32(x1, 13); x1 ^= x0;
  x0 += x1; x1 = rotl32(x1, 15); x1 ^= x0;
  x0 += x1; x1 = rotl32(x1, 26); x1 ^= x0;
  x0 += x1; x1 = rotl32(x1, 6);  x1 ^= x0;
  x0 += k0; x1 += k1 + 3u;
  x0 += x1; x1 = rotl32(x1, 17); x1 ^= x0;
  x0 += x1; x1 = rotl32(x1, 29); x1 ^= x0;
  x0 += x1; x1 = rotl32(x1, 16); x1 ^= x0;
  x0 += x1; x1 = rotl32(x1, 24); x1 ^= x0;
  x0 += k1; x1 += ks2 + 4u;
  x0 += x1; x1 = rotl32(x1, 13); x1 ^= x0;
  x0 += x1; x1 = rotl32(x1, 15); x1 ^= x0;
  x0 += x1; x1 = rotl32(x1, 26); x1 ^= x0;
  x0 += x1; x1 = rotl32(x1, 6);  x1 ^= x0;
  x0 += ks2; x1 += k0 + 5u;
  o0 = x0; o1 = x1;
}

__device__ __forceinline__ float jax_gumbel(uint32_t k0, uint32_t k1, int j) {
  uint32_t o0, o1;
  threefry2x32(k0, k1, 0u, (uint32_t)j, o0, o1);
  uint32_t bits = o0 ^ o1;
  uint32_t ub = (bits >> 9) | 0x3F800000u;
  float u = __uint_as_float(ub) - 1.0f;
  u = fmaxf(u + TINYF, TINYF);
  return -logf(-logf(u));
}

// fast tanh: (1-e)/(1+e), e=exp(-2|x|) in (0,1]; ~2ulp
__device__ __forceinline__ float ftanh(float x) {
  float ax = fabsf(x);
  float e = __expf(-2.0f * ax);
  float r = (1.0f - e) * __builtin_amdgcn_rcpf(1.0f + e);
  return copysignf(r, x);
}

__device__ __forceinline__ float fsig(float x) {
  return __builtin_amdgcn_rcpf(1.0f + __expf(-x));
}

// ---------------- K0: fold dyn path + step keys ----------------
__global__ void k0_dyn(const float* __restrict__ W_att, const float* __restrict__ dyn_w,
                       const float* __restrict__ dyn_b, float* __restrict__ Wd,
                       float* __restrict__ cv, uint32_t* __restrict__ keys) {
  int h = threadIdx.x;  // 128
  if (h < 64) {
    uint32_t o0, o1;
    threefry2x32(0u, 42u, 0u, (uint32_t)h, o0, o1);
    keys[2 * h] = o0; keys[2 * h + 1] = o1;
  }
  float w0 = 0.f, w1 = 0.f, cc = 0.f;
  for (int k = 0; k < HN; ++k) {
    float w = W_att[h * 384 + 128 + k];
    w0 = fmaf(w, dyn_w[2 * k + 0], w0);
    w1 = fmaf(w, dyn_w[2 * k + 1], w1);
    cc = fmaf(w, dyn_b[k], cc);
  }
  Wd[2 * h] = w0; Wd[2 * h + 1] = w1; cv[h] = cc;
}

// ---------------- K1: x-chain (R3 version: 128 thr, in_w in VGPRs) ----------
__global__ __launch_bounds__(128) void k1_xchain(const float* __restrict__ SE,
                                                 const float* __restrict__ in_w,
                                                 const float* __restrict__ in_b,
                                                 float* __restrict__ X) {
  __shared__ float xc[HN];
  int b = blockIdx.x, t = threadIdx.x;
  float wreg[HN];
#pragma unroll
  for (int k = 0; k < HN; k += 4) {
    float4 w4 = *(const float4*)(in_w + t * HN + k);
    wreg[k] = w4.x; wreg[k + 1] = w4.y; wreg[k + 2] = w4.z; wreg[k + 3] = w4.w;
  }
  float bt = in_b[t];
  xc[t] = SE[(b * HN + t) * SN + 0];
  __syncthreads();
  for (int i = 0; i < SN; ++i) {
    float a0 = 0.f, a1 = 0.f, a2 = 0.f, a3 = 0.f;
#pragma unroll
    for (int k = 0; k < HN; k += 4) {
      float4 x4 = *(const float4*)(xc + k);
      a0 = fmaf(wreg[k], x4.x, a0);
      a1 = fmaf(wreg[k + 1], x4.y, a1);
      a2 = fmaf(wreg[k + 2], x4.z, a2);
      a3 = fmaf(wreg[k + 3], x4.w, a3);
    }
    float acc = ((a0 + a1) + (a2 + a3)) + bt;
    X[(i * BN + b) * HN + t] = acc;
    __syncthreads();
    xc[t] = acc;
    __syncthreads();
  }
}

// ---------------- GI = w_ih @ X + b_ih (reg-matvec, 32 n per block) --------
__global__ __launch_bounds__(384) void gemm_gi(const float* __restrict__ X,
                                               const float* __restrict__ w_ih,
                                               const float* __restrict__ b_ih,
                                               float* __restrict__ GI) {
  __shared__ float xs[32 * HN];  // 16 KB
  int n0 = blockIdx.x * 32, t = threadIdx.x;
  float4 wv[32];
#pragma unroll
  for (int kk = 0; kk < 32; ++kk)
    wv[kk] = *(const float4*)(w_ih + t * HN + kk * 4);
  float bt = b_ih[t];
  for (int idx = t; idx < 32 * HN; idx += 384)
    xs[idx] = X[n0 * HN + idx];
  __syncthreads();
  for (int n = 0; n < 32; ++n) {
    const float* xr = xs + n * HN;
    float a0 = 0.f, a1 = 0.f, a2 = 0.f, a3 = 0.f;
#pragma unroll
    for (int kk = 0; kk < 32; ++kk) {
      float4 x4 = *(const float4*)(xr + kk * 4);  // broadcast read
      a0 = fmaf(wv[kk].x, x4.x, a0);
      a1 = fmaf(wv[kk].y, x4.y, a1);
      a2 = fmaf(wv[kk].z, x4.z, a2);
      a3 = fmaf(wv[kk].w, x4.w, a3);
    }
    GI[(n0 + n) * 384 + t] = ((a0 + a1) + (a2 + a3)) + bt;
  }
}

// ---------------- WhC = W_att3 @ h (reg-matvec, M=128) ---------------------
// 256 thr: m = t&127, ng = t>>7 interleaves n (no reduction, no extra barrier)
__global__ __launch_bounds__(256) void gemm_whc(const float* __restrict__ Hs,
                                                const float* __restrict__ W_att,
                                                float* __restrict__ WhC) {
  __shared__ float xs[32 * HN];  // 16 KB
  int n0 = blockIdx.x * 32, t = threadIdx.x;
  int m = t & 127, ng = t >> 7;
  float4 wv[32];
#pragma unroll
  for (int kk = 0; kk < 32; ++kk)
    wv[kk] = *(const float4*)(W_att + m * 384 + 256 + kk * 4);
  for (int idx = t; idx < 32 * HN; idx += 256)
    xs[idx] = Hs[n0 * HN + idx];
  __syncthreads();
  for (int nn = 0; nn < 16; ++nn) {
    int n = nn * 2 + ng;
    const float* xr = xs + n * HN;
    float a0 = 0.f, a1 = 0.f, a2 = 0.f, a3 = 0.f;
#pragma unroll
    for (int kk = 0; kk < 32; ++kk) {
      float4 x4 = *(const float4*)(xr + kk * 4);
      a0 = fmaf(wv[kk].x, x4.x, a0);
      a1 = fmaf(wv[kk].y, x4.y, a1);
      a2 = fmaf(wv[kk].z, x4.z, a2);
      a3 = fmaf(wv[kk].w, x4.w, a3);
    }
    WhC[(n0 + n) * HN + m] = (a0 + a1) + (a2 + a3);
  }
}

// ---------------- Ust = W_att1 @ static_emb (reg-matvec, per-b) ------------
// stage SE[b] transposed [s][k+pad] so inner loop is float4 broadcast reads
__global__ __launch_bounds__(256) void gemm_se2(const float* __restrict__ SE,
                                                const float* __restrict__ W_att,
                                                float* __restrict__ Ust) {
  __shared__ float xs[64 * 129];  // 33 KB
  int b = blockIdx.x, t = threadIdx.x;
  int m = t & 127, sg = t >> 7;
  float4 wv[32];
#pragma unroll
  for (int kk = 0; kk < 32; ++kk)
    wv[kk] = *(const float4*)(W_att + m * 384 + kk * 4);
  for (int idx = t; idx < 8192; idx += 256) {
    int k = idx >> 6, s = idx & 63;
    xs[s * 129 + k] = SE[b * 8192 + idx];   // coalesced read, 2-way LDS write
  }
  __syncthreads();
  for (int ss = 0; ss < 32; ++ss) {
    int s = ss * 2 + sg;
    const float* xr = xs + s * 129;
    float a0 = 0.f, a1 = 0.f, a2 = 0.f, a3 = 0.f;
#pragma unroll
    for (int kk = 0; kk < 32; ++kk) {
      float4 x4 = *(const float4*)(xr + kk * 4);
      a0 = fmaf(wv[kk].x, x4.x, a0);
      a1 = fmaf(wv[kk].y, x4.y, a1);
      a2 = fmaf(wv[kk].z, x4.z, a2);
      a3 = fmaf(wv[kk].w, x4.w, a3);
    }
    Ust[(b * SN + s) * HN + m] = (a0 + a1) + (a2 + a3);
  }
}

// ---------------- K3: h-chain (GRU) with depth-2 GI prefetch ----------------
__global__ __launch_bounds__(384) void k3_hchain(const float* __restrict__ GI,
                                                 const float* __restrict__ w_hh,
                                                 const float* __restrict__ b_hh,
                                                 float* __restrict__ Hs) {
  __shared__ float hc[HN];
  __shared__ float gsh[384];
  __shared__ float gish[384];
  int b = blockIdx.x, t = threadIdx.x;
  float wreg[HN];
#pragma unroll
  for (int k = 0; k < HN; k += 4) {
    float4 w4 = *(const float4*)(w_hh + t * HN + k);
    wreg[k] = w4.x; wreg[k + 1] = w4.y; wreg[k + 2] = w4.z; wreg[k + 3] = w4.w;
  }
  float bt = b_hh[t];
  if (t < HN) hc[t] = 0.f;
  float gv0 = GI[(0 * BN + b) * 384 + t];
  float gv1 = GI[(1 * BN + b) * 384 + t];
  __syncthreads();
  for (int i = 0; i < SN; ++i) {
    float a0 = 0.f, a1 = 0.f, a2 = 0.f, a3 = 0.f;
#pragma unroll
    for (int k = 0; k < HN; k += 4) {
      float4 x4 = *(const float4*)(hc + k);
      a0 = fmaf(wreg[k], x4.x, a0);
      a1 = fmaf(wreg[k + 1], x4.y, a1);
      a2 = fmaf(wreg[k + 2], x4.z, a2);
      a3 = fmaf(wreg[k + 3], x4.w, a3);
    }
    gsh[t] = ((a0 + a1) + (a2 + a3)) + bt;
    gish[t] = gv0;
    gv0 = gv1;
    gv1 = (i + 2 < SN) ? GI[((i + 2) * BN + b) * 384 + t] : 0.f;
    __syncthreads();
    if (t < HN) {
      float r = fsig(gish[t] + gsh[t]);
      float z = fsig(gish[HN + t] + gsh[HN + t]);
      float nn = ftanh(gish[2 * HN + t] + r * gsh[2 * HN + t]);
      float hnew = (1.0f - z) * nn + z * hc[t];
      Hs[(i * BN + b) * HN + t] = hnew;
      hc[t] = hnew;
    }
    __syncthreads();
  }
}

// ---------------- K6: scores P[b][i][s], 8 i per block ----------------
__global__ __launch_bounds__(256) void k6_scores(const float* __restrict__ Ust,
                                                 const float* __restrict__ WhC,
                                                 const float* __restrict__ dynamic,
                                                 const float* __restrict__ Wd,
                                                 const float* __restrict__ cv,
                                                 const float* __restrict__ v_att,
                                                 float* __restrict__ Pg) {
  __shared__ float U[HN * 65];
  __shared__ float Wh[8 * HN];
  __shared__ float sv[HN];
  int b = blockIdx.x, iq = blockIdx.y, t = threadIdx.x;
#pragma unroll
  for (int p = 0; p < 32; ++p) {
    int idx = p * 256 + t;
    int s = idx >> 7, h = idx & 127;
    float u = Ust[(b * SN + s) * HN + h];
    float d0 = dynamic[(b * 2 + 0) * SN + s];
    float d1 = dynamic[(b * 2 + 1) * SN + s];
    u += Wd[2 * h] * d0 + Wd[2 * h + 1] * d1 + cv[h];
    U[h * 65 + s] = u;
  }
#pragma unroll
  for (int p = 0; p < 4; ++p) {
    int idx = p * 256 + t;
    int i = idx >> 7, h = idx & 127;
    Wh[i * HN + h] = WhC[((iq * 8 + i) * BN + b) * HN + h];
  }
  if (t < HN) sv[t] = v_att[t];
  __syncthreads();
  int s = t & 63, w = t >> 6;
  float acc0 = 0.f, acc1 = 0.f;
  for (int h = 0; h < HN; h += 4) {
    float u0 = U[(h + 0) * 65 + s];
    float u1 = U[(h + 1) * 65 + s];
    float u2 = U[(h + 2) * 65 + s];
    float u3 = U[(h + 3) * 65 + s];
    float4 v4 = *(const float4*)&sv[h];
    float4 wa = *(const float4*)&Wh[(w * 2 + 0) * HN + h];
    acc0 = fmaf(v4.x, ftanh(u0 + wa.x), acc0);
    acc0 = fmaf(v4.y, ftanh(u1 + wa.y), acc0);
    acc0 = fmaf(v4.z, ftanh(u2 + wa.z), acc0);
    acc0 = fmaf(v4.w, ftanh(u3 + wa.w), acc0);
    float4 wb = *(const float4*)&Wh[(w * 2 + 1) * HN + h];
    acc1 = fmaf(v4.x, ftanh(u0 + wb.x), acc1);
    acc1 = fmaf(v4.y, ftanh(u1 + wb.y), acc1);
    acc1 = fmaf(v4.z, ftanh(u2 + wb.z), acc1);
    acc1 = fmaf(v4.w, ftanh(u3 + wb.w), acc1);
  }
  int i0 = iq * 8 + w * 2;
  Pg[b * 4096 + (i0 + 0) * 64 + s] = acc0;
  Pg[b * 4096 + (i0 + 1) * 64 + s] = acc1;
}

// ---------------- KG: gumbels (fully parallel) ----------------
__global__ __launch_bounds__(256) void kG_gumbel(const uint32_t* __restrict__ keys,
                                                 float* __restrict__ G) {
  int idx = blockIdx.x * 256 + threadIdx.x;
  int b = idx >> 12;
  int i = (idx >> 6) & 63;
  G[idx] = jax_gumbel(keys[2 * i], keys[2 * i + 1], b * 64 + (idx & 63));
}

// ---------------- K7: sampling (one wave per batch element) ----------------
__global__ __launch_bounds__(256) void k7_sample(const float* __restrict__ Pg,
                                                 const float* __restrict__ Gg,
                                                 float* __restrict__ out) {
  __shared__ float Pl[4096];
  __shared__ float Gl[4096];
  int b = blockIdx.x, t = threadIdx.x;
#pragma unroll
  for (int p = 0; p < 4; ++p) {
    ((float4*)Pl)[p * 256 + t] = ((const float4*)(Pg + b * 4096))[p * 256 + t];
    ((float4*)Gl)[p * 256 + t] = ((const float4*)(Gg + b * 4096))[p * 256 + t];
  }
  __syncthreads();
  if (t < 64) {
    int s = t;
    bool visited = false;
    for (int i = 0; i < SN; ++i) {
      float score = Pl[i * 64 + s];
      bool allowed = (i == 0) ? (s == 0) : (!visited);
      float logit = allowed ? score : NEGV;
      float z = logit + Gl[i * 64 + s];
      float bz = z; int bi = s;
#pragma unroll
      for (int off = 32; off > 0; off >>= 1) {
        float oz = __shfl_xor(bz, off);
        int oi = __shfl_xor(bi, off);
        if (oz > bz || (oz == bz && oi < bi)) { bz = oz; bi = oi; }
      }
      int ptr = bi;
      float m = logit;
#pragma unroll
      for (int off = 32; off > 0; off >>= 1) m = fmaxf(m, __shfl_xor(m, off));
      float e = expf(logit - m);
      float sum = e;
#pragma unroll
      for (int off = 32; off > 0; off >>= 1) sum += __shfl_xor(sum, off);
      float chosen = __shfl(logit, ptr);
      float logp = (chosen - m) - logf(sum);
      if (s == ptr) visited = true;
      if (s == 0) {
        out[b * SN + i] = (float)ptr;
        out[BN * SN + b * SN + i] = logp;
      }
    }
  }
}

// ---------------- launch ----------------
extern "C" void kernel_launch(void* const* d_in, const int* in_sizes, int n_in,
                              void* d_out, int out_size, void* d_ws, size_t ws_size,
                              hipStream_t stream) {
  const float* SE    = (const float*)d_in[1];
  const float* dynam = (const float*)d_in[2];
  const float* dyn_w = (const float*)d_in[3];
  const float* dyn_b = (const float*)d_in[4];
  const float* in_w  = (const float*)d_in[5];
  const float* in_b  = (const float*)d_in[6];
  const float* w_ih  = (const float*)d_in[7];
  const float* w_hh  = (const float*)d_in[8];
  const float* b_ih  = (const float*)d_in[9];
  const float* b_hh  = (const float*)d_in[10];
  const float* W_att = (const float*)d_in[11];
  const float* v_att = (const float*)d_in[12];
  float* out = (float*)d_out;
  float* ws = (float*)d_ws;

  // workspace (floats), lifetime-aliased:
  //  [0, 2M)        X (k1->gemm_gi), Hs (k3->gemm_whc), P (k6->k7)
  //  [2M, 8.39M)    GI (gemm_gi->k3); after k3: WhC @2M, Ust @4.19M, G @6.29M
  //  [8.39M, ...)   Wd, cv, keys
  float* X   = ws;
  float* GI  = ws + 2097152;
  float* WhC = GI;
  float* Ust = ws + 4194304;
  float* G   = ws + 6291456;
  float* Wd  = ws + 8388608;
  float* cv  = Wd + 256;
  uint32_t* keys = (uint32_t*)(cv + 128);
  float* Hs  = X;
  float* P   = X;

  hipLaunchKernelGGL(k0_dyn, dim3(1), dim3(128), 0, stream, W_att, dyn_w, dyn_b, Wd, cv, keys);
  hipLaunchKernelGGL(k1_xchain, dim3(BN), dim3(128), 0, stream, SE, in_w, in_b, X);
  hipLaunchKernelGGL(gemm_gi, dim3(512), dim3(384), 0, stream, X, w_ih, b_ih, GI);
  hipLaunchKernelGGL(k3_hchain, dim3(BN), dim3(384), 0, stream, GI, w_hh, b_hh, Hs);
  hipLaunchKernelGGL(kG_gumbel, dim3(4096), dim3(256), 0, stream, keys, G);
  hipLaunchKernelGGL(gemm_whc, dim3(512), dim3(256), 0, stream, Hs, W_att, WhC);
  hipLaunchKernelGGL(gemm_se2, dim3(BN), dim3(256), 0, stream, SE, W_att, Ust);
  hipLaunchKernelGGL(k6_scores, dim3(BN, 8), dim3(256), 0, stream,
                     Ust, WhC, dynam, Wd, cv, v_att, P);
  hipLaunchKernelGGL(k7_sample, dim3(BN), dim3(256), 0, stream, P, G, out);
}

// Round 6
// 415.023 us; speedup vs baseline: 1.4448x; 1.4448x over previous
//
#include <hip/hip_runtime.h>
#include <stdint.h>

// PointerNetwork forward, MI355X/gfx950.
// x-chain and h-chain are sampling-independent; scores for unvisited slots
// don't depend on WHICH slots are visited => precompute all, sample cheaply.
// B=256, S=64, H=128.
// RNG: JAX threefry2x32 partitionable mode: bits = o0^o1 of tf(key,(0,j)).
//
// GEMM history: R4 LDS-tile (98us, bank conflicts), R5 reg-matvec w/ 128-VGPR
// weights (147us, spills: WRITE 56MB vs 25MB ideal). R6 design: 4-way K-split
// => 64 VGPR weights (no spill), conflict-free broadcast b128 LDS reads,
// shfl_xor(1/2) reduce within 4-lane groups.

#define BN 256
#define SN 64
#define HN 128
#define NEGV (-1.0e9f)
#define TINYF 1.17549435e-38f

__device__ __forceinline__ uint32_t rotl32(uint32_t v, int d) {
  return (v << d) | (v >> (32 - d));
}

__device__ __forceinline__ void threefry2x32(uint32_t k0, uint32_t k1,
                                             uint32_t x0, uint32_t x1,
                                             uint32_t& o0, uint32_t& o1) {
  uint32_t ks2 = k0 ^ k1 ^ 0x1BD11BDAu;
  x0 += k0; x1 += k1;
  x0 += x1; x1 = rotl32(x1, 13); x1 ^= x0;
  x0 += x1; x1 = rotl32(x1, 15); x1 ^= x0;
  x0 += x1; x1 = rotl32(x1, 26); x1 ^= x0;
  x0 += x1; x1 = rotl32(x1, 6);  x1 ^= x0;
  x0 += k1; x1 += ks2 + 1u;
  x0 += x1; x1 = rotl32(x1, 17); x1 ^= x0;
  x0 += x1; x1 = rotl32(x1, 29); x1 ^= x0;
  x0 += x1; x1 = rotl32(x1, 16); x1 ^= x0;
  x0 += x1; x1 = rotl32(x1, 24); x1 ^= x0;
  x0 += ks2; x1 += k0 + 2u;
  x0 += x1; x1 = rotl32(x1, 13); x1 ^= x0;
  x0 += x1; x1 = rotl32(x1, 15); x1 ^= x0;
  x0 += x1; x1 = rotl32(x1, 26); x1 ^= x0;
  x0 += x1; x1 = rotl32(x1, 6);  x1 ^= x0;
  x0 += k0; x1 += k1 + 3u;
  x0 += x1; x1 = rotl32(x1, 17); x1 ^= x0;
  x0 += x1; x1 = rotl32(x1, 29); x1 ^= x0;
  x0 += x1; x1 = rotl32(x1, 16); x1 ^= x0;
  x0 += x1; x1 = rotl32(x1, 24); x1 ^= x0;
  x0 += k1; x1 += ks2 + 4u;
  x0 += x1; x1 = rotl32(x1, 13); x1 ^= x0;
  x0 += x1; x1 = rotl32(x1, 15); x1 ^= x0;
  x0 += x1; x1 = rotl32(x1, 26); x1 ^= x0;
  x0 += x1; x1 = rotl32(x1, 6);  x1 ^= x0;
  x0 += ks2; x1 += k0 + 5u;
  o0 = x0; o1 = x1;
}

__device__ __forceinline__ float jax_gumbel(uint32_t k0, uint32_t k1, int j) {
  uint32_t o0, o1;
  threefry2x32(k0, k1, 0u, (uint32_t)j, o0, o1);
  uint32_t bits = o0 ^ o1;
  uint32_t ub = (bits >> 9) | 0x3F800000u;
  float u = __uint_as_float(ub) - 1.0f;
  u = fmaxf(u + TINYF, TINYF);
  return -logf(-logf(u));
}

// fast tanh: (1-e)/(1+e), e=exp(-2|x|) in (0,1]; ~2ulp
__device__ __forceinline__ float ftanh(float x) {
  float ax = fabsf(x);
  float e = __expf(-2.0f * ax);
  float r = (1.0f - e) * __builtin_amdgcn_rcpf(1.0f + e);
  return copysignf(r, x);
}

__device__ __forceinline__ float fsig(float x) {
  return __builtin_amdgcn_rcpf(1.0f + __expf(-x));
}

// ---------------- K0: fold dyn path + step keys ----------------
__global__ void k0_dyn(const float* __restrict__ W_att, const float* __restrict__ dyn_w,
                       const float* __restrict__ dyn_b, float* __restrict__ Wd,
                       float* __restrict__ cv, uint32_t* __restrict__ keys) {
  int h = threadIdx.x;  // 128
  if (h < 64) {
    uint32_t o0, o1;
    threefry2x32(0u, 42u, 0u, (uint32_t)h, o0, o1);
    keys[2 * h] = o0; keys[2 * h + 1] = o1;
  }
  float w0 = 0.f, w1 = 0.f, cc = 0.f;
  for (int k = 0; k < HN; ++k) {
    float w = W_att[h * 384 + 128 + k];
    w0 = fmaf(w, dyn_w[2 * k + 0], w0);
    w1 = fmaf(w, dyn_w[2 * k + 1], w1);
    cc = fmaf(w, dyn_b[k], cc);
  }
  Wd[2 * h] = w0; Wd[2 * h + 1] = w1; cv[h] = cc;
}

// ---------------- K1: x-chain (128 thr, in_w in VGPRs) ----------
__global__ __launch_bounds__(128) void k1_xchain(const float* __restrict__ SE,
                                                 const float* __restrict__ in_w,
                                                 const float* __restrict__ in_b,
                                                 float* __restrict__ X) {
  __shared__ float xc[HN];
  int b = blockIdx.x, t = threadIdx.x;
  float wreg[HN];
#pragma unroll
  for (int k = 0; k < HN; k += 4) {
    float4 w4 = *(const float4*)(in_w + t * HN + k);
    wreg[k] = w4.x; wreg[k + 1] = w4.y; wreg[k + 2] = w4.z; wreg[k + 3] = w4.w;
  }
  float bt = in_b[t];
  xc[t] = SE[(b * HN + t) * SN + 0];
  __syncthreads();
  for (int i = 0; i < SN; ++i) {
    float a0 = 0.f, a1 = 0.f, a2 = 0.f, a3 = 0.f;
#pragma unroll
    for (int k = 0; k < HN; k += 4) {
      float4 x4 = *(const float4*)(xc + k);
      a0 = fmaf(wreg[k], x4.x, a0);
      a1 = fmaf(wreg[k + 1], x4.y, a1);
      a2 = fmaf(wreg[k + 2], x4.z, a2);
      a3 = fmaf(wreg[k + 3], x4.w, a3);
    }
    float acc = ((a0 + a1) + (a2 + a3)) + bt;
    X[(i * BN + b) * HN + t] = acc;
    __syncthreads();
    xc[t] = acc;
    __syncthreads();
  }
}

// ---------------- universal GEMM: C[n][m] = sum_k A[n][k]*W[m][wofs+k] ------
// block 256 = 64 ml x 4 ks. Thread: m-rows {mo+ml, mo+64+ml}, K-quarter
// k = ks*4 + kk*16 + j (kk 0..7, j 0..3). 64 VGPR weights. 4-lane shfl reduce.
__global__ __launch_bounds__(256, 3) void gemm_u(const float* __restrict__ A,
                                                 const float* __restrict__ W,
                                                 const float* __restrict__ bias,
                                                 float* __restrict__ C,
                                                 int ldw, int wofs, int Mtot) {
  __shared__ float4 xsv[64 * 32];  // 64 n-rows x 128 k (32 KB)
  int n0 = blockIdx.x * 64, mo = blockIdx.y * 128;
  int t = threadIdx.x, ml = t >> 2, ks = t & 3;
  int m0 = mo + ml, m1 = mo + 64 + ml;
  float4 wv0[8], wv1[8];
#pragma unroll
  for (int kk = 0; kk < 8; ++kk) {
    wv0[kk] = *(const float4*)(W + m0 * ldw + wofs + kk * 16 + ks * 4);
    wv1[kk] = *(const float4*)(W + m1 * ldw + wofs + kk * 16 + ks * 4);
  }
  float b0 = bias ? bias[m0] : 0.f;
  float b1 = bias ? bias[m1] : 0.f;
  const float4* Av = (const float4*)(A + n0 * HN);
#pragma unroll
  for (int p = 0; p < 8; ++p) xsv[p * 256 + t] = Av[p * 256 + t];
  __syncthreads();
  for (int n = 0; n < 64; ++n) {
    const float4* xr = xsv + n * 32 + ks;
    float a00 = 0.f, a01 = 0.f, a10 = 0.f, a11 = 0.f;
#pragma unroll
    for (int kk = 0; kk < 8; ++kk) {
      float4 x4 = xr[kk * 4];   // 4 unique addrs, 16 disjoint banks, bcast
      a00 = fmaf(wv0[kk].x, x4.x, a00);
      a01 = fmaf(wv0[kk].y, x4.y, a01);
      a00 = fmaf(wv0[kk].z, x4.z, a00);
      a01 = fmaf(wv0[kk].w, x4.w, a01);
      a10 = fmaf(wv1[kk].x, x4.x, a10);
      a11 = fmaf(wv1[kk].y, x4.y, a11);
      a10 = fmaf(wv1[kk].z, x4.z, a10);
      a11 = fmaf(wv1[kk].w, x4.w, a11);
    }
    float v0 = a00 + a01, v1 = a10 + a11;
    v0 += __shfl_xor(v0, 1); v0 += __shfl_xor(v0, 2);
    v1 += __shfl_xor(v1, 1); v1 += __shfl_xor(v1, 2);
    if (ks == 0) {
      C[(n0 + n) * Mtot + m0] = v0 + b0;
      C[(n0 + n) * Mtot + m1] = v1 + b1;
    }
  }
}

// ---------------- kT: SET[(b*64+s)*128+h] = SE[b][h][s] (LDS transpose) -----
__global__ __launch_bounds__(256) void kT(const float* __restrict__ SE,
                                          float* __restrict__ SET) {
  __shared__ float ls[HN * 66];
  int b = blockIdx.x, t = threadIdx.x;
#pragma unroll
  for (int p = 0; p < 32; ++p) {
    int idx = p * 256 + t;
    int h = idx >> 6, s = idx & 63;
    ls[h * 66 + s] = SE[b * 8192 + idx];
  }
  __syncthreads();
#pragma unroll
  for (int p = 0; p < 32; ++p) {
    int idx = p * 256 + t;
    int s = idx >> 7, h = idx & 127;
    SET[b * 8192 + idx] = ls[h * 66 + s];  // bank (2h+s)%32: 2-way, free
  }
}

// ---------------- K3: h-chain (GRU) with depth-2 GI prefetch ----------------
__global__ __launch_bounds__(384) void k3_hchain(const float* __restrict__ GI,
                                                 const float* __restrict__ w_hh,
                                                 const float* __restrict__ b_hh,
                                                 float* __restrict__ Hs) {
  __shared__ float hc[HN];
  __shared__ float gsh[384];
  __shared__ float gish[384];
  int b = blockIdx.x, t = threadIdx.x;
  float wreg[HN];
#pragma unroll
  for (int k = 0; k < HN; k += 4) {
    float4 w4 = *(const float4*)(w_hh + t * HN + k);
    wreg[k] = w4.x; wreg[k + 1] = w4.y; wreg[k + 2] = w4.z; wreg[k + 3] = w4.w;
  }
  float bt = b_hh[t];
  if (t < HN) hc[t] = 0.f;
  float gv0 = GI[(0 * BN + b) * 384 + t];
  float gv1 = GI[(1 * BN + b) * 384 + t];
  __syncthreads();
  for (int i = 0; i < SN; ++i) {
    float a0 = 0.f, a1 = 0.f, a2 = 0.f, a3 = 0.f;
#pragma unroll
    for (int k = 0; k < HN; k += 4) {
      float4 x4 = *(const float4*)(hc + k);
      a0 = fmaf(wreg[k], x4.x, a0);
      a1 = fmaf(wreg[k + 1], x4.y, a1);
      a2 = fmaf(wreg[k + 2], x4.z, a2);
      a3 = fmaf(wreg[k + 3], x4.w, a3);
    }
    gsh[t] = ((a0 + a1) + (a2 + a3)) + bt;
    gish[t] = gv0;
    gv0 = gv1;
    gv1 = (i + 2 < SN) ? GI[((i + 2) * BN + b) * 384 + t] : 0.f;
    __syncthreads();
    if (t < HN) {
      float r = fsig(gish[t] + gsh[t]);
      float z = fsig(gish[HN + t] + gsh[HN + t]);
      float nn = ftanh(gish[2 * HN + t] + r * gsh[2 * HN + t]);
      float hnew = (1.0f - z) * nn + z * hc[t];
      Hs[(i * BN + b) * HN + t] = hnew;
      hc[t] = hnew;
    }
    __syncthreads();
  }
}

// ---------------- K6: scores P[b][i][s], 8 i per block ----------------
__global__ __launch_bounds__(256) void k6_scores(const float* __restrict__ Ust,
                                                 const float* __restrict__ WhC,
                                                 const float* __restrict__ dynamic,
                                                 const float* __restrict__ Wd,
                                                 const float* __restrict__ cv,
                                                 const float* __restrict__ v_att,
                                                 float* __restrict__ Pg) {
  __shared__ float U[HN * 65];
  __shared__ float Wh[8 * HN];
  __shared__ float sv[HN];
  int b = blockIdx.x, iq = blockIdx.y, t = threadIdx.x;
#pragma unroll
  for (int p = 0; p < 32; ++p) {
    int idx = p * 256 + t;
    int s = idx >> 7, h = idx & 127;
    float u = Ust[(b * SN + s) * HN + h];
    float d0 = dynamic[(b * 2 + 0) * SN + s];
    float d1 = dynamic[(b * 2 + 1) * SN + s];
    u += Wd[2 * h] * d0 + Wd[2 * h + 1] * d1 + cv[h];
    U[h * 65 + s] = u;
  }
#pragma unroll
  for (int p = 0; p < 4; ++p) {
    int idx = p * 256 + t;
    int i = idx >> 7, h = idx & 127;
    Wh[i * HN + h] = WhC[((iq * 8 + i) * BN + b) * HN + h];
  }
  if (t < HN) sv[t] = v_att[t];
  __syncthreads();
  int s = t & 63, w = t >> 6;
  float acc0 = 0.f, acc1 = 0.f;
  for (int h = 0; h < HN; h += 4) {
    float u0 = U[(h + 0) * 65 + s];
    float u1 = U[(h + 1) * 65 + s];
    float u2 = U[(h + 2) * 65 + s];
    float u3 = U[(h + 3) * 65 + s];
    float4 v4 = *(const float4*)&sv[h];
    float4 wa = *(const float4*)&Wh[(w * 2 + 0) * HN + h];
    acc0 = fmaf(v4.x, ftanh(u0 + wa.x), acc0);
    acc0 = fmaf(v4.y, ftanh(u1 + wa.y), acc0);
    acc0 = fmaf(v4.z, ftanh(u2 + wa.z), acc0);
    acc0 = fmaf(v4.w, ftanh(u3 + wa.w), acc0);
    float4 wb = *(const float4*)&Wh[(w * 2 + 1) * HN + h];
    acc1 = fmaf(v4.x, ftanh(u0 + wb.x), acc1);
    acc1 = fmaf(v4.y, ftanh(u1 + wb.y), acc1);
    acc1 = fmaf(v4.z, ftanh(u2 + wb.z), acc1);
    acc1 = fmaf(v4.w, ftanh(u3 + wb.w), acc1);
  }
  int i0 = iq * 8 + w * 2;
  Pg[b * 4096 + (i0 + 0) * 64 + s] = acc0;
  Pg[b * 4096 + (i0 + 1) * 64 + s] = acc1;
}

// ---------------- K7: gumbel + sampling (one wave per batch element) --------
__global__ __launch_bounds__(256) void k7_sample(const float* __restrict__ Pg,
                                                 const uint32_t* __restrict__ keys,
                                                 float* __restrict__ out) {
  __shared__ float Pl[4096];
  __shared__ float Gl[4096];
  int b = blockIdx.x, t = threadIdx.x;
#pragma unroll
  for (int p = 0; p < 4; ++p)
    ((float4*)Pl)[p * 256 + t] = ((const float4*)(Pg + b * 4096))[p * 256 + t];
  for (int p = 0; p < 16; ++p) {
    int idx = p * 256 + t;
    int i = idx >> 6;
    Gl[idx] = jax_gumbel(keys[2 * i], keys[2 * i + 1], b * 64 + (idx & 63));
  }
  __syncthreads();
  if (t < 64) {
    int s = t;
    bool visited = false;
    for (int i = 0; i < SN; ++i) {
      float score = Pl[i * 64 + s];
      bool allowed = (i == 0) ? (s == 0) : (!visited);
      float logit = allowed ? score : NEGV;
      float z = logit + Gl[i * 64 + s];
      float bz = z; int bi = s;
#pragma unroll
      for (int off = 32; off > 0; off >>= 1) {
        float oz = __shfl_xor(bz, off);
        int oi = __shfl_xor(bi, off);
        if (oz > bz || (oz == bz && oi < bi)) { bz = oz; bi = oi; }
      }
      int ptr = bi;
      float m = logit;
#pragma unroll
      for (int off = 32; off > 0; off >>= 1) m = fmaxf(m, __shfl_xor(m, off));
      float e = expf(logit - m);
      float sum = e;
#pragma unroll
      for (int off = 32; off > 0; off >>= 1) sum += __shfl_xor(sum, off);
      float chosen = __shfl(logit, ptr);
      float logp = (chosen - m) - logf(sum);
      if (s == ptr) visited = true;
      if (s == 0) {
        out[b * SN + i] = (float)ptr;
        out[BN * SN + b * SN + i] = logp;
      }
    }
  }
}

// ---------------- launch ----------------
extern "C" void kernel_launch(void* const* d_in, const int* in_sizes, int n_in,
                              void* d_out, int out_size, void* d_ws, size_t ws_size,
                              hipStream_t stream) {
  const float* SE    = (const float*)d_in[1];
  const float* dynam = (const float*)d_in[2];
  const float* dyn_w = (const float*)d_in[3];
  const float* dyn_b = (const float*)d_in[4];
  const float* in_w  = (const float*)d_in[5];
  const float* in_b  = (const float*)d_in[6];
  const float* w_ih  = (const float*)d_in[7];
  const float* w_hh  = (const float*)d_in[8];
  const float* b_ih  = (const float*)d_in[9];
  const float* b_hh  = (const float*)d_in[10];
  const float* W_att = (const float*)d_in[11];
  const float* v_att = (const float*)d_in[12];
  float* out = (float*)d_out;
  float* ws = (float*)d_ws;

  // workspace (floats), lifetime-aliased (33.6 MB total, same as R3):
  //  [0, 2M)           X (k1->gemm GI), Hs (k3->gemm WhC), P (k6->k7)
  //  [2M, 8.29M)       GI (gemm->k3); after k3: SET@2M, WhC@4M, Ust@6M
  //  [8.39M, +)        Wd, cv, keys
  float* X   = ws;
  float* GI  = ws + 2097152;
  float* SET = ws + 2097152;
  float* WhC = ws + 4194304;
  float* Ust = ws + 6291456;
  float* Wd  = ws + 8388608;
  float* cv  = Wd + 256;
  uint32_t* keys = (uint32_t*)(cv + 128);
  float* Hs  = X;
  float* P   = X;

  hipLaunchKernelGGL(k0_dyn, dim3(1), dim3(128), 0, stream, W_att, dyn_w, dyn_b, Wd, cv, keys);
  hipLaunchKernelGGL(k1_xchain, dim3(BN), dim3(128), 0, stream, SE, in_w, in_b, X);
  // GI = w_ih @ X + b_ih   (M=384)
  hipLaunchKernelGGL(gemm_u, dim3(256, 3), dim3(256), 0, stream,
                     X, w_ih, b_ih, GI, HN, 0, 384);
  hipLaunchKernelGGL(k3_hchain, dim3(BN), dim3(384), 0, stream, GI, w_hh, b_hh, Hs);
  hipLaunchKernelGGL(kT, dim3(BN), dim3(256), 0, stream, SE, SET);
  // WhC = W_att3 @ h   (M=128)
  hipLaunchKernelGGL(gemm_u, dim3(256, 1), dim3(256), 0, stream,
                     Hs, W_att, (const float*)nullptr, WhC, 384, 256, HN);
  // Ust = W_att1 @ SE^T   (M=128)
  hipLaunchKernelGGL(gemm_u, dim3(256, 1), dim3(256), 0, stream,
                     SET, W_att, (const float*)nullptr, Ust, 384, 0, HN);
  hipLaunchKernelGGL(k6_scores, dim3(BN, 8), dim3(256), 0, stream,
                     Ust, WhC, dynam, Wd, cv, v_att, P);
  hipLaunchKernelGGL(k7_sample, dim3(BN), dim3(256), 0, stream, P, keys, out);
}